// Round 6
// baseline (386.690 us; speedup 1.0000x reference)
//
#include <hip/hip_runtime.h>
#include <math.h>

#define B_ 256
#define K_ 256
#define H_ 128
#define I_ 64
#define O_ 64
#define NU 6
#define BP 64    // particles per block (4 waves x 16)
#define MW 16    // particles per wave

typedef short bf16x8 __attribute__((ext_vector_type(8)));  // 8 bf16 in 4 VGPRs
typedef float f32x4  __attribute__((ext_vector_type(4)));

// RNE float->bf16 bits
__device__ __forceinline__ unsigned short f2bf(float f) {
  unsigned int u = __builtin_bit_cast(unsigned int, f);
  unsigned int r = (u + 0x7FFFu + ((u >> 16) & 1u)) >> 16;
  return (unsigned short)r;
}

// XOR-swizzled byte offset in a [rows][128] bf16 tile (row stride 256B, T2-style).
__device__ __forceinline__ unsigned int swz(unsigned int row, unsigned int col) {
  return (row * 256u + col * 2u) ^ ((row & 15u) << 4);
}

__device__ __forceinline__ float tanh_fast(float x) {
  float e = __expf(2.0f * x);
  return 1.0f - 2.0f * __builtin_amdgcn_rcpf(e + 1.0f);
}

// ---------------- propagation kernel (bf16 MFMA, dim-major D layout) ----------------
// D = Wh^T @ S^T per 16x16 tile: lane owns particle col (lr) and 4 contiguous dims
// (lg*4+r) -> noise/particle I/O is float4, state writeback is ds_write_b64.
__global__ __launch_bounds__(256, 3) void prop_kernel(
    const float* __restrict__ x,          // [B,I]
    const float* __restrict__ particles,  // [B*K,H]
    const float* __restrict__ noise,      // [B*K,NU,H]
    const float* __restrict__ Wx,         // [I,H]
    const float* __restrict__ Wh,         // [H,H]
    const float* __restrict__ bvec,       // [H]
    const float* __restrict__ log_sigma,  // [H]
    float* __restrict__ p_out)            // [B*K,H]
{
  __shared__ __align__(16) unsigned short whT[H_ * H_]; // bf16 Wh^T [c][k], swizzled, 32KB
  __shared__ __align__(16) unsigned short sS[BP * H_];  // bf16 state [p][d], swizzled, 16KB
  __shared__ __align__(16) float xwx[H_];
  __shared__ __align__(16) float gsd[H_];

  const int tid  = threadIdx.x;
  const int lane = tid & 63;
  const int wave = tid >> 6;
  const int bk0  = blockIdx.x * BP;
  const int b    = bk0 >> 8;            // /K_
  const int lr   = lane & 15;           // particle col within wave tile
  const int lg   = lane >> 4;           // dim group 0..3

  const int myp = bk0 + wave * MW + lr; // this lane's particle row
  const float* prow = particles + (size_t)myp * H_ + lg * 4;
  const float* nrow = noise + (size_t)myp * NU * H_ + lg * 4;
  float* orow = p_out + (size_t)myp * H_ + lg * 4;

  // ---- issue early: initial state + first-unfold noise (overlaps staging) ----
  f32x4 s4[8], nA[8], nB[8];
#pragma unroll
  for (int ct = 0; ct < 8; ++ct) s4[ct] = ((const f32x4*)prow)[ct * 4];
#pragma unroll
  for (int ct = 0; ct < 8; ++ct) nA[ct] = ((const f32x4*)nrow)[ct * 4];

  // ---- stage Wh^T as bf16 (swizzled) ----
#pragma unroll
  for (int it = 0; it < 16; ++it) {
    int idx = tid + it * 256;           // float4 index over Wh [k][c]
    int k   = idx >> 5;
    int c0  = (idx & 31) * 4;
    float4 v = ((const float4*)Wh)[idx];
    float vv[4] = {v.x, v.y, v.z, v.w};
#pragma unroll
    for (int e = 0; e < 4; ++e)
      *(unsigned short*)((char*)whT + swz(c0 + e, k)) = f2bf(vv[e]);
  }
  // ---- xwx = x@Wx + b, gsd = softplus(log_sigma)*sqrt(dt) ----
  if (tid < H_) {
    float acc = bvec[tid];
#pragma unroll 8
    for (int i = 0; i < I_; ++i) acc = fmaf(x[b * I_ + i], Wx[i * H_ + tid], acc);
    xwx[tid] = acc;
    gsd[tid] = log1pf(expf(log_sigma[tid])) * sqrtf(1.0f / 6.0f);
  }
  __syncthreads();

  const float dt = 1.0f / 6.0f;
  const int srow = wave * MW + lr;      // this lane's sS row

  auto loadN = [&](f32x4* buf, int n_) {
    const f32x4* np = (const f32x4*)(nrow + (size_t)n_ * H_);
#pragma unroll
    for (int ct = 0; ct < 8; ++ct) buf[ct] = np[ct * 4];
  };

  auto step = [&](const f32x4* nb) {
    // 1) write fp32 master -> sS bf16 (own rows only: no barrier needed)
#pragma unroll
    for (int ct = 0; ct < 8; ++ct) {
      unsigned lo = (unsigned)f2bf(s4[ct][0]) | ((unsigned)f2bf(s4[ct][1]) << 16);
      unsigned hi = (unsigned)f2bf(s4[ct][2]) | ((unsigned)f2bf(s4[ct][3]) << 16);
      uint2 pk = {lo, hi};
      *(uint2*)((char*)sS + swz(srow, ct * 16 + lg * 4)) = pk;
    }
    // 2) B-fragments: S^T (own particle row)
    bf16x8 bfrag[4];
#pragma unroll
    for (int kt = 0; kt < 4; ++kt)
      bfrag[kt] = *(const bf16x8*)((char*)sS + swz(srow, kt * 32 + lg * 8));
    // 3) per 16-dim tile: D = xwx + Wh^T_tile @ S^T, then EM update
#pragma unroll
    for (int ct = 0; ct < 8; ++ct) {
      f32x4 acc = *(const f32x4*)&xwx[ct * 16 + lg * 4];
#pragma unroll
      for (int kt = 0; kt < 4; ++kt) {
        bf16x8 afrag = *(const bf16x8*)((char*)whT + swz(ct * 16 + lr, kt * 32 + lg * 8));
        acc = __builtin_amdgcn_mfma_f32_16x16x32_bf16(afrag, bfrag[kt], acc, 0, 0, 0);
      }
      f32x4 gs = *(const f32x4*)&gsd[ct * 16 + lg * 4];
#pragma unroll
      for (int r = 0; r < 4; ++r) {
        float t  = tanh_fast(acc[r]);
        float sv = s4[ct][r];
        s4[ct][r] = fmaf(t - sv, dt, sv) + gs[r] * nb[ct][r];
      }
    }
  };

#pragma unroll 1
  for (int h = 0; h < 3; ++h) {         // unfolds 2h, 2h+1; noise prefetched 1 ahead
    loadN(nB, 2 * h + 1);
    step(nA);
    if (h < 2) loadN(nA, 2 * h + 2);
    step(nB);
  }

  // write new particles (fp32, float4 coalesced)
#pragma unroll
  for (int ct = 0; ct < 8; ++ct) ((f32x4*)orow)[ct * 4] = s4[ct];
}

// ---------------- resampling + weighted output kernel ----------------
__device__ __forceinline__ float blk_max(float v, float* red, int k){
  red[k]=v; __syncthreads();
  for (int off=128; off>0; off>>=1){ if (k<off) red[k]=fmaxf(red[k],red[k+off]); __syncthreads(); }
  float r = red[0]; __syncthreads(); return r;
}
__device__ __forceinline__ float blk_sum(float v, float* red, int k){
  red[k]=v; __syncthreads();
  for (int off=128; off>0; off>>=1){ if (k<off) red[k]+=red[k+off]; __syncthreads(); }
  float r = red[0]; __syncthreads(); return r;
}

// one block per batch, 256 threads = K particles
__global__ __launch_bounds__(256) void finish_kernel(
  const float* __restrict__ log_weights,   // [B,K]
  const float* __restrict__ resample_u,    // [B,K]
  const float* __restrict__ W_out,         // [H,O]
  const float* __restrict__ b_out,         // [O]
  const float* __restrict__ alpha_logit,   // [1]
  float* __restrict__ p,                   // [B*K,H] new particles (in d_out)
  float* __restrict__ out0,                // [B,O]
  float* __restrict__ lw_out)              // [B,K]
{
  const int b = blockIdx.x, k = threadIdx.x;
  __shared__ float red[K_];
  __shared__ float lw[K_], qv[K_], cdf[K_], wt[K_];
  __shared__ float ws_h[H_];

  float lwk = log_weights[b*K_ + k];
  float mx  = blk_max(lwk, red, k);
  float se  = blk_sum(expf(lwk - mx), red, k);
  float lse = mx + logf(se);
  float lwn = lwk - lse;
  lw[k] = lwn;
  float w = expf(lwn);
  float sw2 = blk_sum(w*w, red, k);
  float ess = 1.0f / sw2;

  float alpha = 1.0f/(1.0f + expf(-alpha_logit[0]));
  float qk = alpha*w + (1.0f-alpha)*(1.0f/K_);
  qv[k] = qk;
  cdf[k] = qk; __syncthreads();
  for (int off=1; off<K_; off<<=1){
    float add = (k>=off)? cdf[k-off] : 0.0f;
    __syncthreads();
    cdf[k] += add;
    __syncthreads();
  }
  float u = resample_u[b*K_ + k];
  int lo=0, cnt=K_;
  while (cnt>0){ int st=cnt>>1; if (cdf[lo+st] < u){ lo += st+1; cnt -= st+1; } else cnt = st; }
  int idx = min(lo, K_-1);

  float lr  = lw[idx] - logf(qv[idx]);
  float mx2 = blk_max(lr, red, k);
  float se2 = blk_sum(expf(lr-mx2), red, k);
  float lrn = lr - (mx2 + logf(se2));

  bool need = ess < 0.5f * K_;
  float flw = need ? lrn : lwn;
  lw_out[b*K_ + k] = flw;

  float mx3 = blk_max(flw, red, k);
  float se3 = blk_sum(expf(flw-mx3), red, k);
  float wk  = expf(flw - (mx3 + logf(se3)));
  wt[k] = wk;
  float sumw = blk_sum(wk, red, k);

  int h = k & (H_-1), half = k >> 7;
  float part = 0.f;
  const float* pb = &p[(size_t)b*K_*H_];
  for (int kk = half*128; kk < half*128 + 128; ++kk)
    part = fmaf(wt[kk], pb[(size_t)kk*H_ + h], part);
  red[k] = part; __syncthreads();
  if (k < H_) ws_h[k] = red[k] + red[k+H_];
  __syncthreads();

  if (k < O_) {
    float acc = sumw * b_out[k];
#pragma unroll 8
    for (int hh = 0; hh < H_; ++hh) acc = fmaf(ws_h[hh], W_out[hh*O_ + k], acc);
    out0[b*O_ + k] = acc;
  }

  if (need) {
    const float* src = &p[((size_t)b*K_ + idx)*H_];
    float* dstp      = &p[((size_t)b*K_ + k  )*H_];
    float tmp[16];
    for (int c = 0; c < H_; c += 16){
#pragma unroll
      for (int t=0;t<16;++t) tmp[t]=src[c+t];
      __syncthreads();
#pragma unroll
      for (int t=0;t<16;++t) dstp[c+t]=tmp[t];
      __syncthreads();
    }
  }
}

extern "C" void kernel_launch(void* const* d_in, const int* in_sizes, int n_in,
                              void* d_out, int out_size, void* d_ws, size_t ws_size,
                              hipStream_t stream) {
  const float* x           = (const float*)d_in[0];
  const float* particles   = (const float*)d_in[1];
  const float* log_weights = (const float*)d_in[2];
  const float* noise       = (const float*)d_in[3];
  const float* resample_u  = (const float*)d_in[4];
  const float* Wx          = (const float*)d_in[5];
  const float* Wh          = (const float*)d_in[6];
  const float* bvec        = (const float*)d_in[7];
  const float* log_sigma   = (const float*)d_in[8];
  const float* W_out       = (const float*)d_in[9];
  const float* b_out       = (const float*)d_in[10];
  const float* alpha_logit = (const float*)d_in[11];

  float* out0   = (float*)d_out;
  float* p_out  = out0 + B_*O_;
  float* lw_out = p_out + (size_t)B_*K_*H_;

  prop_kernel<<<(B_*K_)/BP, 256, 0, stream>>>(
      x, particles, noise, Wx, Wh, bvec, log_sigma, p_out);
  finish_kernel<<<B_, 256, 0, stream>>>(
      log_weights, resample_u, W_out, b_out, alpha_logit, p_out, out0, lw_out);
}

// Round 7
// 298.230 us; speedup vs baseline: 1.2966x; 1.2966x over previous
//
#include <hip/hip_runtime.h>
#include <math.h>

#define B_ 256
#define K_ 256
#define H_ 128
#define I_ 64
#define O_ 64
#define NU 6
#define BP 64    // particles per block (4 waves x 16)
#define MW 16    // particles per wave

typedef short bf16x8 __attribute__((ext_vector_type(8)));  // 8 bf16 in 4 VGPRs
typedef float f32x4  __attribute__((ext_vector_type(4)));

// RNE float->bf16 bits
__device__ __forceinline__ unsigned short f2bf(float f) {
  unsigned int u = __builtin_bit_cast(unsigned int, f);
  unsigned int r = (u + 0x7FFFu + ((u >> 16) & 1u)) >> 16;
  return (unsigned short)r;
}

// XOR-swizzled byte offset in a [rows][128] bf16 tile (row stride 256B, T2-style).
__device__ __forceinline__ unsigned int swz(unsigned int row, unsigned int col) {
  return (row * 256u + col * 2u) ^ ((row & 15u) << 4);
}

__device__ __forceinline__ float tanh_fast(float x) {
  float e = __expf(2.0f * x);
  return 1.0f - 2.0f * __builtin_amdgcn_rcpf(e + 1.0f);
}

// ---------------- propagation kernel (bf16 MFMA, dim-major D layout) ----------------
// D = Wh^T @ S^T per 16x16 tile: lane owns particle col (lr) and 4 contiguous dims
// (lg*4+r) -> noise/particle I/O is float4, state writeback is ds_write_b64.
// launch_bounds(256,2): round 6's (256,3) capped VGPRs at 84 -> scratch spills
// (+450MB fetch / +312MB write of spill traffic). 2 waves/SIMD, no spill.
__global__ __launch_bounds__(256, 2) void prop_kernel(
    const float* __restrict__ x,          // [B,I]
    const float* __restrict__ particles,  // [B*K,H]
    const float* __restrict__ noise,      // [B*K,NU,H]
    const float* __restrict__ Wx,         // [I,H]
    const float* __restrict__ Wh,         // [H,H]
    const float* __restrict__ bvec,       // [H]
    const float* __restrict__ log_sigma,  // [H]
    float* __restrict__ p_out)            // [B*K,H]
{
  __shared__ __align__(16) unsigned short whT[H_ * H_]; // bf16 Wh^T [c][k], swizzled, 32KB
  __shared__ __align__(16) unsigned short sS[BP * H_];  // bf16 state [p][d], swizzled, 16KB
  __shared__ __align__(16) float xwx[H_];
  __shared__ __align__(16) float gsd[H_];

  const int tid  = threadIdx.x;
  const int lane = tid & 63;
  const int wave = tid >> 6;
  const int bk0  = blockIdx.x * BP;
  const int b    = bk0 >> 8;            // /K_
  const int lr   = lane & 15;           // particle col within wave tile
  const int lg   = lane >> 4;           // dim group 0..3

  const int myp = bk0 + wave * MW + lr; // this lane's particle row
  const float* prow = particles + (size_t)myp * H_ + lg * 4;
  const float* nrow = noise + (size_t)myp * NU * H_ + lg * 4;
  float* orow = p_out + (size_t)myp * H_ + lg * 4;

  // ---- issue early: initial state + first-unfold noise (overlaps staging) ----
  f32x4 s4[8], nA[8], nB[8];
#pragma unroll
  for (int ct = 0; ct < 8; ++ct) s4[ct] = ((const f32x4*)prow)[ct * 4];
#pragma unroll
  for (int ct = 0; ct < 8; ++ct) nA[ct] = ((const f32x4*)nrow)[ct * 4];

  // ---- stage Wh^T as bf16 (swizzled) ----
#pragma unroll
  for (int it = 0; it < 16; ++it) {
    int idx = tid + it * 256;           // float4 index over Wh [k][c]
    int k   = idx >> 5;
    int c0  = (idx & 31) * 4;
    float4 v = ((const float4*)Wh)[idx];
    float vv[4] = {v.x, v.y, v.z, v.w};
#pragma unroll
    for (int e = 0; e < 4; ++e)
      *(unsigned short*)((char*)whT + swz(c0 + e, k)) = f2bf(vv[e]);
  }
  // ---- xwx = x@Wx + b, gsd = softplus(log_sigma)*sqrt(dt) ----
  if (tid < H_) {
    float acc = bvec[tid];
#pragma unroll 8
    for (int i = 0; i < I_; ++i) acc = fmaf(x[b * I_ + i], Wx[i * H_ + tid], acc);
    xwx[tid] = acc;
    gsd[tid] = log1pf(expf(log_sigma[tid])) * sqrtf(1.0f / 6.0f);
  }
  __syncthreads();

  const float dt = 1.0f / 6.0f;
  const int srow = wave * MW + lr;      // this lane's sS row

  auto loadN = [&](f32x4* buf, int n_) {
    const f32x4* np = (const f32x4*)(nrow + (size_t)n_ * H_);
#pragma unroll
    for (int ct = 0; ct < 8; ++ct) buf[ct] = np[ct * 4];
  };

  auto step = [&](const f32x4* nb) {
    // 1) write fp32 master -> sS bf16 (own rows only: no barrier needed)
#pragma unroll
    for (int ct = 0; ct < 8; ++ct) {
      unsigned lo = (unsigned)f2bf(s4[ct][0]) | ((unsigned)f2bf(s4[ct][1]) << 16);
      unsigned hi = (unsigned)f2bf(s4[ct][2]) | ((unsigned)f2bf(s4[ct][3]) << 16);
      uint2 pk = {lo, hi};
      *(uint2*)((char*)sS + swz(srow, ct * 16 + lg * 4)) = pk;
    }
    // 2) B-fragments: S^T (own particle row)
    bf16x8 bfrag[4];
#pragma unroll
    for (int kt = 0; kt < 4; ++kt)
      bfrag[kt] = *(const bf16x8*)((char*)sS + swz(srow, kt * 32 + lg * 8));
    // 3) per 16-dim tile: D = xwx + Wh^T_tile @ S^T, then EM update
#pragma unroll
    for (int ct = 0; ct < 8; ++ct) {
      f32x4 acc = *(const f32x4*)&xwx[ct * 16 + lg * 4];
#pragma unroll
      for (int kt = 0; kt < 4; ++kt) {
        bf16x8 afrag = *(const bf16x8*)((char*)whT + swz(ct * 16 + lr, kt * 32 + lg * 8));
        acc = __builtin_amdgcn_mfma_f32_16x16x32_bf16(afrag, bfrag[kt], acc, 0, 0, 0);
      }
      f32x4 gs = *(const f32x4*)&gsd[ct * 16 + lg * 4];
#pragma unroll
      for (int r = 0; r < 4; ++r) {
        float t  = tanh_fast(acc[r]);
        float sv = s4[ct][r];
        s4[ct][r] = fmaf(t - sv, dt, sv) + gs[r] * nb[ct][r];
      }
    }
  };

#pragma unroll 1
  for (int h = 0; h < 3; ++h) {         // unfolds 2h, 2h+1; noise prefetched 1 ahead
    loadN(nB, 2 * h + 1);
    step(nA);
    if (h < 2) loadN(nA, 2 * h + 2);
    step(nB);
  }

  // write new particles (fp32, float4 coalesced)
#pragma unroll
  for (int ct = 0; ct < 8; ++ct) ((f32x4*)orow)[ct * 4] = s4[ct];
}

// ---------------- resampling + weighted output kernel ----------------
__device__ __forceinline__ float blk_max(float v, float* red, int k){
  red[k]=v; __syncthreads();
  for (int off=128; off>0; off>>=1){ if (k<off) red[k]=fmaxf(red[k],red[k+off]); __syncthreads(); }
  float r = red[0]; __syncthreads(); return r;
}
__device__ __forceinline__ float blk_sum(float v, float* red, int k){
  red[k]=v; __syncthreads();
  for (int off=128; off>0; off>>=1){ if (k<off) red[k]+=red[k+off]; __syncthreads(); }
  float r = red[0]; __syncthreads(); return r;
}

// one block per batch, 256 threads = K particles
__global__ __launch_bounds__(256) void finish_kernel(
  const float* __restrict__ log_weights,   // [B,K]
  const float* __restrict__ resample_u,    // [B,K]
  const float* __restrict__ W_out,         // [H,O]
  const float* __restrict__ b_out,         // [O]
  const float* __restrict__ alpha_logit,   // [1]
  float* __restrict__ p,                   // [B*K,H] new particles (in d_out)
  float* __restrict__ out0,                // [B,O]
  float* __restrict__ lw_out)              // [B,K]
{
  const int b = blockIdx.x, k = threadIdx.x;
  __shared__ float red[K_];
  __shared__ float lw[K_], qv[K_], cdf[K_], wt[K_];
  __shared__ float ws_h[H_];

  float lwk = log_weights[b*K_ + k];
  float mx  = blk_max(lwk, red, k);
  float se  = blk_sum(expf(lwk - mx), red, k);
  float lse = mx + logf(se);
  float lwn = lwk - lse;
  lw[k] = lwn;
  float w = expf(lwn);
  float sw2 = blk_sum(w*w, red, k);
  float ess = 1.0f / sw2;

  float alpha = 1.0f/(1.0f + expf(-alpha_logit[0]));
  float qk = alpha*w + (1.0f-alpha)*(1.0f/K_);
  qv[k] = qk;
  cdf[k] = qk; __syncthreads();
  for (int off=1; off<K_; off<<=1){
    float add = (k>=off)? cdf[k-off] : 0.0f;
    __syncthreads();
    cdf[k] += add;
    __syncthreads();
  }
  float u = resample_u[b*K_ + k];
  int lo=0, cnt=K_;
  while (cnt>0){ int st=cnt>>1; if (cdf[lo+st] < u){ lo += st+1; cnt -= st+1; } else cnt = st; }
  int idx = min(lo, K_-1);

  float lr  = lw[idx] - logf(qv[idx]);
  float mx2 = blk_max(lr, red, k);
  float se2 = blk_sum(expf(lr-mx2), red, k);
  float lrn = lr - (mx2 + logf(se2));

  bool need = ess < 0.5f * K_;
  float flw = need ? lrn : lwn;
  lw_out[b*K_ + k] = flw;

  float mx3 = blk_max(flw, red, k);
  float se3 = blk_sum(expf(flw-mx3), red, k);
  float wk  = expf(flw - (mx3 + logf(se3)));
  wt[k] = wk;
  float sumw = blk_sum(wk, red, k);

  int h = k & (H_-1), half = k >> 7;
  float part = 0.f;
  const float* pb = &p[(size_t)b*K_*H_];
  for (int kk = half*128; kk < half*128 + 128; ++kk)
    part = fmaf(wt[kk], pb[(size_t)kk*H_ + h], part);
  red[k] = part; __syncthreads();
  if (k < H_) ws_h[k] = red[k] + red[k+H_];
  __syncthreads();

  if (k < O_) {
    float acc = sumw * b_out[k];
#pragma unroll 8
    for (int hh = 0; hh < H_; ++hh) acc = fmaf(ws_h[hh], W_out[hh*O_ + k], acc);
    out0[b*O_ + k] = acc;
  }

  if (need) {
    const float* src = &p[((size_t)b*K_ + idx)*H_];
    float* dstp      = &p[((size_t)b*K_ + k  )*H_];
    float tmp[16];
    for (int c = 0; c < H_; c += 16){
#pragma unroll
      for (int t=0;t<16;++t) tmp[t]=src[c+t];
      __syncthreads();
#pragma unroll
      for (int t=0;t<16;++t) dstp[c+t]=tmp[t];
      __syncthreads();
    }
  }
}

extern "C" void kernel_launch(void* const* d_in, const int* in_sizes, int n_in,
                              void* d_out, int out_size, void* d_ws, size_t ws_size,
                              hipStream_t stream) {
  const float* x           = (const float*)d_in[0];
  const float* particles   = (const float*)d_in[1];
  const float* log_weights = (const float*)d_in[2];
  const float* noise       = (const float*)d_in[3];
  const float* resample_u  = (const float*)d_in[4];
  const float* Wx          = (const float*)d_in[5];
  const float* Wh          = (const float*)d_in[6];
  const float* bvec        = (const float*)d_in[7];
  const float* log_sigma   = (const float*)d_in[8];
  const float* W_out       = (const float*)d_in[9];
  const float* b_out       = (const float*)d_in[10];
  const float* alpha_logit = (const float*)d_in[11];

  float* out0   = (float*)d_out;
  float* p_out  = out0 + B_*O_;
  float* lw_out = p_out + (size_t)B_*K_*H_;

  prop_kernel<<<(B_*K_)/BP, 256, 0, stream>>>(
      x, particles, noise, Wx, Wh, bvec, log_sigma, p_out);
  finish_kernel<<<B_, 256, 0, stream>>>(
      log_weights, resample_u, W_out, b_out, alpha_logit, p_out, out0, lw_out);
}

// Round 8
// 108.114 us; speedup vs baseline: 3.5767x; 2.7585x over previous
//
#include <hip/hip_runtime.h>
#include <math.h>

#define B_ 256
#define K_ 256
#define H_ 128
#define I_ 64
#define O_ 64
#define NU 6
#define BP 64    // particles per block (4 waves x 16)
#define MW 16    // particles per wave

typedef short bf16x8 __attribute__((ext_vector_type(8)));  // 8 bf16 in 4 VGPRs
typedef float f32x4  __attribute__((ext_vector_type(4)));

// RNE float->bf16 bits
__device__ __forceinline__ unsigned short f2bf(float f) {
  unsigned int u = __builtin_bit_cast(unsigned int, f);
  unsigned int r = (u + 0x7FFFu + ((u >> 16) & 1u)) >> 16;
  return (unsigned short)r;
}

// XOR-swizzled byte offset in a [rows][128] bf16 tile (row stride 256B, T2-style).
__device__ __forceinline__ unsigned int swz(unsigned int row, unsigned int col) {
  return (row * 256u + col * 2u) ^ ((row & 15u) << 4);
}

__device__ __forceinline__ float tanh_fast(float x) {
  float e = __expf(2.0f * x);
  return 1.0f - 2.0f * __builtin_amdgcn_rcpf(e + 1.0f);
}

// ---------------- propagation kernel (bf16 MFMA, dim-major D layout) ----------------
// D = Wh^T @ S^T per 16x16 tile: lane owns particle col (lr) and 4 contiguous dims.
// R7 lesson: lambdas taking f32x4* forced nA/nB to scratch (341MB write traffic).
// All buffer access is now via MACROS on named arrays -> fully static -> registers.
// No waves-per-eu bound: allocator free to use ~170 VGPRs with zero spill.
__global__ __launch_bounds__(256) void prop_kernel(
    const float* __restrict__ x,          // [B,I]
    const float* __restrict__ particles,  // [B*K,H]
    const float* __restrict__ noise,      // [B*K,NU,H]
    const float* __restrict__ Wx,         // [I,H]
    const float* __restrict__ Wh,         // [H,H]
    const float* __restrict__ bvec,       // [H]
    const float* __restrict__ log_sigma,  // [H]
    float* __restrict__ p_out)            // [B*K,H]
{
  __shared__ __align__(16) unsigned short whT[H_ * H_]; // bf16 Wh^T [c][k], swizzled, 32KB
  __shared__ __align__(16) unsigned short sS[BP * H_];  // bf16 state [p][d], swizzled, 16KB
  __shared__ __align__(16) float xwx[H_];
  __shared__ __align__(16) float gsd[H_];

  const int tid  = threadIdx.x;
  const int lane = tid & 63;
  const int wave = tid >> 6;
  const int bk0  = blockIdx.x * BP;
  const int b    = bk0 >> 8;            // /K_
  const int lr   = lane & 15;           // particle col within wave tile
  const int lg   = lane >> 4;           // dim group 0..3

  const int myp = bk0 + wave * MW + lr; // this lane's particle row
  const float* prow = particles + (size_t)myp * H_ + lg * 4;
  const float* nrow = noise + (size_t)myp * NU * H_ + lg * 4;
  float* orow = p_out + (size_t)myp * H_ + lg * 4;

  // ---- issue early: initial state + first-unfold noise (overlaps staging) ----
  f32x4 s4[8], nA[8], nB[8];
#pragma unroll
  for (int ct = 0; ct < 8; ++ct) s4[ct] = ((const f32x4*)prow)[ct * 4];
#pragma unroll
  for (int ct = 0; ct < 8; ++ct) nA[ct] = ((const f32x4*)nrow)[ct * 4];

  // ---- stage Wh^T as bf16 (swizzled) ----
#pragma unroll
  for (int it = 0; it < 16; ++it) {
    int idx = tid + it * 256;           // float4 index over Wh [k][c]
    int k   = idx >> 5;
    int c0  = (idx & 31) * 4;
    float4 v = ((const float4*)Wh)[idx];
    float vv[4] = {v.x, v.y, v.z, v.w};
#pragma unroll
    for (int e = 0; e < 4; ++e)
      *(unsigned short*)((char*)whT + swz(c0 + e, k)) = f2bf(vv[e]);
  }
  // ---- xwx = x@Wx + b, gsd = softplus(log_sigma)*sqrt(dt) ----
  if (tid < H_) {
    float acc = bvec[tid];
#pragma unroll 8
    for (int i = 0; i < I_; ++i) acc = fmaf(x[b * I_ + i], Wx[i * H_ + tid], acc);
    xwx[tid] = acc;
    gsd[tid] = log1pf(expf(log_sigma[tid])) * sqrtf(1.0f / 6.0f);
  }
  __syncthreads();

  const float dt = 1.0f / 6.0f;
  const int srow = wave * MW + lr;      // this lane's sS row

// macros keep all buffer accesses on NAMED arrays (static -> registers)
#define LOADN(buf, n_) do {                                                  \
    const f32x4* np = (const f32x4*)(nrow + (size_t)(n_) * H_);              \
    _Pragma("unroll")                                                        \
    for (int ct = 0; ct < 8; ++ct) buf[ct] = np[ct * 4];                     \
  } while (0)

#define STEP(nb) do {                                                        \
    _Pragma("unroll")                                                        \
    for (int ct = 0; ct < 8; ++ct) {                                         \
      unsigned lo_ = (unsigned)f2bf(s4[ct][0]) | ((unsigned)f2bf(s4[ct][1]) << 16); \
      unsigned hi_ = (unsigned)f2bf(s4[ct][2]) | ((unsigned)f2bf(s4[ct][3]) << 16); \
      uint2 pk_ = {lo_, hi_};                                                \
      *(uint2*)((char*)sS + swz(srow, ct * 16 + lg * 4)) = pk_;              \
    }                                                                        \
    bf16x8 bfrag0 = *(const bf16x8*)((char*)sS + swz(srow, 0 * 32 + lg * 8));\
    bf16x8 bfrag1 = *(const bf16x8*)((char*)sS + swz(srow, 1 * 32 + lg * 8));\
    bf16x8 bfrag2 = *(const bf16x8*)((char*)sS + swz(srow, 2 * 32 + lg * 8));\
    bf16x8 bfrag3 = *(const bf16x8*)((char*)sS + swz(srow, 3 * 32 + lg * 8));\
    _Pragma("unroll")                                                        \
    for (int ct = 0; ct < 8; ++ct) {                                         \
      f32x4 acc = *(const f32x4*)&xwx[ct * 16 + lg * 4];                     \
      bf16x8 af0 = *(const bf16x8*)((char*)whT + swz(ct * 16 + lr, 0 * 32 + lg * 8)); \
      acc = __builtin_amdgcn_mfma_f32_16x16x32_bf16(af0, bfrag0, acc, 0, 0, 0); \
      bf16x8 af1 = *(const bf16x8*)((char*)whT + swz(ct * 16 + lr, 1 * 32 + lg * 8)); \
      acc = __builtin_amdgcn_mfma_f32_16x16x32_bf16(af1, bfrag1, acc, 0, 0, 0); \
      bf16x8 af2 = *(const bf16x8*)((char*)whT + swz(ct * 16 + lr, 2 * 32 + lg * 8)); \
      acc = __builtin_amdgcn_mfma_f32_16x16x32_bf16(af2, bfrag2, acc, 0, 0, 0); \
      bf16x8 af3 = *(const bf16x8*)((char*)whT + swz(ct * 16 + lr, 3 * 32 + lg * 8)); \
      acc = __builtin_amdgcn_mfma_f32_16x16x32_bf16(af3, bfrag3, acc, 0, 0, 0); \
      f32x4 gs = *(const f32x4*)&gsd[ct * 16 + lg * 4];                      \
      _Pragma("unroll")                                                      \
      for (int r = 0; r < 4; ++r) {                                          \
        float t_  = tanh_fast(acc[r]);                                       \
        float sv_ = s4[ct][r];                                               \
        s4[ct][r] = fmaf(t_ - sv_, dt, sv_) + gs[r] * nb[ct][r];             \
      }                                                                      \
    }                                                                        \
  } while (0)

  // straight-line 6 unfolds, noise prefetched one step ahead (named dbuf)
  LOADN(nB, 1); STEP(nA);
  LOADN(nA, 2); STEP(nB);
  LOADN(nB, 3); STEP(nA);
  LOADN(nA, 4); STEP(nB);
  LOADN(nB, 5); STEP(nA);
  STEP(nB);

#undef LOADN
#undef STEP

  // write new particles (fp32, float4 coalesced)
#pragma unroll
  for (int ct = 0; ct < 8; ++ct) ((f32x4*)orow)[ct * 4] = s4[ct];
}

// ---------------- resampling + weighted output kernel ----------------
__device__ __forceinline__ float blk_max(float v, float* red, int k){
  red[k]=v; __syncthreads();
  for (int off=128; off>0; off>>=1){ if (k<off) red[k]=fmaxf(red[k],red[k+off]); __syncthreads(); }
  float r = red[0]; __syncthreads(); return r;
}
__device__ __forceinline__ float blk_sum(float v, float* red, int k){
  red[k]=v; __syncthreads();
  for (int off=128; off>0; off>>=1){ if (k<off) red[k]+=red[k+off]; __syncthreads(); }
  float r = red[0]; __syncthreads(); return r;
}

// one block per batch, 256 threads = K particles
__global__ __launch_bounds__(256) void finish_kernel(
  const float* __restrict__ log_weights,   // [B,K]
  const float* __restrict__ resample_u,    // [B,K]
  const float* __restrict__ W_out,         // [H,O]
  const float* __restrict__ b_out,         // [O]
  const float* __restrict__ alpha_logit,   // [1]
  float* __restrict__ p,                   // [B*K,H] new particles (in d_out)
  float* __restrict__ out0,                // [B,O]
  float* __restrict__ lw_out)              // [B,K]
{
  const int b = blockIdx.x, k = threadIdx.x;
  __shared__ float red[K_];
  __shared__ float lw[K_], qv[K_], cdf[K_], wt[K_];
  __shared__ float ws_h[H_];

  float lwk = log_weights[b*K_ + k];
  float mx  = blk_max(lwk, red, k);
  float se  = blk_sum(expf(lwk - mx), red, k);
  float lse = mx + logf(se);
  float lwn = lwk - lse;
  lw[k] = lwn;
  float w = expf(lwn);
  float sw2 = blk_sum(w*w, red, k);
  float ess = 1.0f / sw2;

  float alpha = 1.0f/(1.0f + expf(-alpha_logit[0]));
  float qk = alpha*w + (1.0f-alpha)*(1.0f/K_);
  qv[k] = qk;
  cdf[k] = qk; __syncthreads();
  for (int off=1; off<K_; off<<=1){
    float add = (k>=off)? cdf[k-off] : 0.0f;
    __syncthreads();
    cdf[k] += add;
    __syncthreads();
  }
  float u = resample_u[b*K_ + k];
  int lo=0, cnt=K_;
  while (cnt>0){ int st=cnt>>1; if (cdf[lo+st] < u){ lo += st+1; cnt -= st+1; } else cnt = st; }
  int idx = min(lo, K_-1);

  float lr  = lw[idx] - logf(qv[idx]);
  float mx2 = blk_max(lr, red, k);
  float se2 = blk_sum(expf(lr-mx2), red, k);
  float lrn = lr - (mx2 + logf(se2));

  bool need = ess < 0.5f * K_;
  float flw = need ? lrn : lwn;
  lw_out[b*K_ + k] = flw;

  float mx3 = blk_max(flw, red, k);
  float se3 = blk_sum(expf(flw-mx3), red, k);
  float wk  = expf(flw - (mx3 + logf(se3)));
  wt[k] = wk;
  float sumw = blk_sum(wk, red, k);

  int h = k & (H_-1), half = k >> 7;
  float part = 0.f;
  const float* pb = &p[(size_t)b*K_*H_];
  for (int kk = half*128; kk < half*128 + 128; ++kk)
    part = fmaf(wt[kk], pb[(size_t)kk*H_ + h], part);
  red[k] = part; __syncthreads();
  if (k < H_) ws_h[k] = red[k] + red[k+H_];
  __syncthreads();

  if (k < O_) {
    float acc = sumw * b_out[k];
#pragma unroll 8
    for (int hh = 0; hh < H_; ++hh) acc = fmaf(ws_h[hh], W_out[hh*O_ + k], acc);
    out0[b*O_ + k] = acc;
  }

  if (need) {
    const float* src = &p[((size_t)b*K_ + idx)*H_];
    float* dstp      = &p[((size_t)b*K_ + k  )*H_];
    float tmp[16];
    for (int c = 0; c < H_; c += 16){
#pragma unroll
      for (int t=0;t<16;++t) tmp[t]=src[c+t];
      __syncthreads();
#pragma unroll
      for (int t=0;t<16;++t) dstp[c+t]=tmp[t];
      __syncthreads();
    }
  }
}

extern "C" void kernel_launch(void* const* d_in, const int* in_sizes, int n_in,
                              void* d_out, int out_size, void* d_ws, size_t ws_size,
                              hipStream_t stream) {
  const float* x           = (const float*)d_in[0];
  const float* particles   = (const float*)d_in[1];
  const float* log_weights = (const float*)d_in[2];
  const float* noise       = (const float*)d_in[3];
  const float* resample_u  = (const float*)d_in[4];
  const float* Wx          = (const float*)d_in[5];
  const float* Wh          = (const float*)d_in[6];
  const float* bvec        = (const float*)d_in[7];
  const float* log_sigma   = (const float*)d_in[8];
  const float* W_out       = (const float*)d_in[9];
  const float* b_out       = (const float*)d_in[10];
  const float* alpha_logit = (const float*)d_in[11];

  float* out0   = (float*)d_out;
  float* p_out  = out0 + B_*O_;
  float* lw_out = p_out + (size_t)B_*K_*H_;

  prop_kernel<<<(B_*K_)/BP, 256, 0, stream>>>(
      x, particles, noise, Wx, Wh, bvec, log_sigma, p_out);
  finish_kernel<<<B_, 256, 0, stream>>>(
      log_weights, resample_u, W_out, b_out, alpha_logit, p_out, out0, lw_out);
}

// Round 9
// 105.554 us; speedup vs baseline: 3.6634x; 1.0242x over previous
//
#include <hip/hip_runtime.h>
#include <math.h>

#define B_ 256
#define K_ 256
#define H_ 128
#define I_ 64
#define O_ 64
#define NU 6
#define BP 64    // particles per block (4 waves x 16)
#define MW 16    // particles per wave

typedef short bf16x8 __attribute__((ext_vector_type(8)));  // 8 bf16 in 4 VGPRs
typedef float f32x4  __attribute__((ext_vector_type(4)));

// RNE float->bf16 bits
__device__ __forceinline__ unsigned short f2bf(float f) {
  unsigned int u = __builtin_bit_cast(unsigned int, f);
  unsigned int r = (u + 0x7FFFu + ((u >> 16) & 1u)) >> 16;
  return (unsigned short)r;
}

// XOR-swizzled byte offset in a [rows][128] bf16 tile (row stride 256B, T2-style).
__device__ __forceinline__ unsigned int swz(unsigned int row, unsigned int col) {
  return (row * 256u + col * 2u) ^ ((row & 15u) << 4);
}

__device__ __forceinline__ float tanh_fast(float x) {
  float e = __expf(2.0f * x);
  return 1.0f - 2.0f * __builtin_amdgcn_rcpf(e + 1.0f);
}

// ---------------- propagation kernel (bf16 MFMA, dim-major D layout) ----------------
// D = Wh^T @ S^T per 16x16 tile: lane owns particle col (lr) and 4 contiguous dims.
// R7/R8 lesson: all register buffers are NAMED arrays accessed via macros (static
// indexing -> registers; pointer-parameter lambdas forced scratch: +760MB traffic).
// R9: 3-buffer noise prefetch -> 2 load-sets in flight (~800cy cover vs ~900cy HBM).
__global__ __launch_bounds__(256) void prop_kernel(
    const float* __restrict__ x,          // [B,I]
    const float* __restrict__ particles,  // [B*K,H]
    const float* __restrict__ noise,      // [B*K,NU,H]
    const float* __restrict__ Wx,         // [I,H]
    const float* __restrict__ Wh,         // [H,H]
    const float* __restrict__ bvec,       // [H]
    const float* __restrict__ log_sigma,  // [H]
    float* __restrict__ p_out)            // [B*K,H]
{
  __shared__ __align__(16) unsigned short whT[H_ * H_]; // bf16 Wh^T [c][k], swizzled, 32KB
  __shared__ __align__(16) unsigned short sS[BP * H_];  // bf16 state [p][d], swizzled, 16KB
  __shared__ __align__(16) float xwx[H_];
  __shared__ __align__(16) float gsd[H_];

  const int tid  = threadIdx.x;
  const int lane = tid & 63;
  const int wave = tid >> 6;
  const int bk0  = blockIdx.x * BP;
  const int b    = bk0 >> 8;            // /K_
  const int lr   = lane & 15;           // particle col within wave tile
  const int lg   = lane >> 4;           // dim group 0..3

  const int myp = bk0 + wave * MW + lr; // this lane's particle row
  const float* prow = particles + (size_t)myp * H_ + lg * 4;
  const float* nrow = noise + (size_t)myp * NU * H_ + lg * 4;
  float* orow = p_out + (size_t)myp * H_ + lg * 4;

  // ---- issue early: initial state + first-unfold noise (overlaps staging) ----
  f32x4 s4[8], nA[8], nB[8], nC[8];
#pragma unroll
  for (int ct = 0; ct < 8; ++ct) s4[ct] = ((const f32x4*)prow)[ct * 4];
#pragma unroll
  for (int ct = 0; ct < 8; ++ct) nA[ct] = ((const f32x4*)nrow)[ct * 4];

  // ---- stage Wh^T as bf16 (swizzled) ----
#pragma unroll
  for (int it = 0; it < 16; ++it) {
    int idx = tid + it * 256;           // float4 index over Wh [k][c]
    int k   = idx >> 5;
    int c0  = (idx & 31) * 4;
    float4 v = ((const float4*)Wh)[idx];
    float vv[4] = {v.x, v.y, v.z, v.w};
#pragma unroll
    for (int e = 0; e < 4; ++e)
      *(unsigned short*)((char*)whT + swz(c0 + e, k)) = f2bf(vv[e]);
  }
  // ---- xwx = x@Wx + b, gsd = softplus(log_sigma)*sqrt(dt) ----
  if (tid < H_) {
    float acc = bvec[tid];
#pragma unroll 8
    for (int i = 0; i < I_; ++i) acc = fmaf(x[b * I_ + i], Wx[i * H_ + tid], acc);
    xwx[tid] = acc;
    gsd[tid] = log1pf(expf(log_sigma[tid])) * sqrtf(1.0f / 6.0f);
  }
  __syncthreads();

  const float dt = 1.0f / 6.0f;
  const int srow = wave * MW + lr;      // this lane's sS row

// macros keep all buffer accesses on NAMED arrays (static -> registers)
#define LOADN(buf, n_) do {                                                  \
    const f32x4* np = (const f32x4*)(nrow + (size_t)(n_) * H_);              \
    _Pragma("unroll")                                                        \
    for (int ct = 0; ct < 8; ++ct) buf[ct] = np[ct * 4];                     \
  } while (0)

#define STEP(nb) do {                                                        \
    _Pragma("unroll")                                                        \
    for (int ct = 0; ct < 8; ++ct) {                                         \
      unsigned lo_ = (unsigned)f2bf(s4[ct][0]) | ((unsigned)f2bf(s4[ct][1]) << 16); \
      unsigned hi_ = (unsigned)f2bf(s4[ct][2]) | ((unsigned)f2bf(s4[ct][3]) << 16); \
      uint2 pk_ = {lo_, hi_};                                                \
      *(uint2*)((char*)sS + swz(srow, ct * 16 + lg * 4)) = pk_;              \
    }                                                                        \
    bf16x8 bfrag0 = *(const bf16x8*)((char*)sS + swz(srow, 0 * 32 + lg * 8));\
    bf16x8 bfrag1 = *(const bf16x8*)((char*)sS + swz(srow, 1 * 32 + lg * 8));\
    bf16x8 bfrag2 = *(const bf16x8*)((char*)sS + swz(srow, 2 * 32 + lg * 8));\
    bf16x8 bfrag3 = *(const bf16x8*)((char*)sS + swz(srow, 3 * 32 + lg * 8));\
    _Pragma("unroll")                                                        \
    for (int ct = 0; ct < 8; ++ct) {                                         \
      f32x4 acc = *(const f32x4*)&xwx[ct * 16 + lg * 4];                     \
      bf16x8 af0 = *(const bf16x8*)((char*)whT + swz(ct * 16 + lr, 0 * 32 + lg * 8)); \
      acc = __builtin_amdgcn_mfma_f32_16x16x32_bf16(af0, bfrag0, acc, 0, 0, 0); \
      bf16x8 af1 = *(const bf16x8*)((char*)whT + swz(ct * 16 + lr, 1 * 32 + lg * 8)); \
      acc = __builtin_amdgcn_mfma_f32_16x16x32_bf16(af1, bfrag1, acc, 0, 0, 0); \
      bf16x8 af2 = *(const bf16x8*)((char*)whT + swz(ct * 16 + lr, 2 * 32 + lg * 8)); \
      acc = __builtin_amdgcn_mfma_f32_16x16x32_bf16(af2, bfrag2, acc, 0, 0, 0); \
      bf16x8 af3 = *(const bf16x8*)((char*)whT + swz(ct * 16 + lr, 3 * 32 + lg * 8)); \
      acc = __builtin_amdgcn_mfma_f32_16x16x32_bf16(af3, bfrag3, acc, 0, 0, 0); \
      f32x4 gs = *(const f32x4*)&gsd[ct * 16 + lg * 4];                      \
      _Pragma("unroll")                                                      \
      for (int r = 0; r < 4; ++r) {                                          \
        float t_  = tanh_fast(acc[r]);                                       \
        float sv_ = s4[ct][r];                                               \
        s4[ct][r] = fmaf(t_ - sv_, dt, sv_) + gs[r] * nb[ct][r];             \
      }                                                                      \
    }                                                                        \
  } while (0)

  // straight-line 6 unfolds, noise prefetched TWO steps ahead (3 named buffers)
  LOADN(nB, 1); LOADN(nC, 2);
  STEP(nA); LOADN(nA, 3);
  STEP(nB); LOADN(nB, 4);
  STEP(nC); LOADN(nC, 5);
  STEP(nA);
  STEP(nB);
  STEP(nC);

#undef LOADN
#undef STEP

  // write new particles (fp32, float4 coalesced)
#pragma unroll
  for (int ct = 0; ct < 8; ++ct) ((f32x4*)orow)[ct * 4] = s4[ct];
}

// ---------------- resampling + weighted output kernel ----------------
// R9: wave-level shuffle reductions (2 barriers each) replace the 16-barrier
// LDS trees (6 calls x 16 = 96 barriers -> 12).
__device__ __forceinline__ float wave_sum(float v) {
#pragma unroll
  for (int off = 1; off < 64; off <<= 1) v += __shfl_xor(v, off, 64);
  return v;
}
__device__ __forceinline__ float wave_max(float v) {
#pragma unroll
  for (int off = 1; off < 64; off <<= 1) v = fmaxf(v, __shfl_xor(v, off, 64));
  return v;
}

// one block per batch, 256 threads = K particles
__global__ __launch_bounds__(256) void finish_kernel(
  const float* __restrict__ log_weights,   // [B,K]
  const float* __restrict__ resample_u,    // [B,K]
  const float* __restrict__ W_out,         // [H,O]
  const float* __restrict__ b_out,         // [O]
  const float* __restrict__ alpha_logit,   // [1]
  float* __restrict__ p,                   // [B*K,H] new particles (in d_out)
  float* __restrict__ out0,                // [B,O]
  float* __restrict__ lw_out)              // [B,K]
{
  const int b = blockIdx.x, k = threadIdx.x;
  const int wv = k >> 6;
  __shared__ float red[K_];
  __shared__ float lw[K_], qv[K_], cdf[K_], wt[K_];
  __shared__ float ws_h[H_];
  __shared__ float warr[4];

#define BLK_SUM(dst, v) do {                                   \
    float pw_ = wave_sum(v);                                   \
    __syncthreads();  /* protect warr reuse */                 \
    if ((k & 63) == 0) warr[wv] = pw_;                         \
    __syncthreads();                                           \
    dst = warr[0] + warr[1] + warr[2] + warr[3];               \
  } while (0)
#define BLK_MAX(dst, v) do {                                   \
    float pw_ = wave_max(v);                                   \
    __syncthreads();                                           \
    if ((k & 63) == 0) warr[wv] = pw_;                         \
    __syncthreads();                                           \
    dst = fmaxf(fmaxf(warr[0], warr[1]), fmaxf(warr[2], warr[3])); \
  } while (0)

  float lwk = log_weights[b*K_ + k];
  float mx;  BLK_MAX(mx, lwk);
  float se;  BLK_SUM(se, expf(lwk - mx));
  float lse = mx + logf(se);
  float lwn = lwk - lse;
  lw[k] = lwn;
  float w = expf(lwn);
  float sw2; BLK_SUM(sw2, w*w);          // barriers inside make lw[] visible
  float ess = 1.0f / sw2;

  float alpha = 1.0f/(1.0f + expf(-alpha_logit[0]));
  float qk = alpha*w + (1.0f-alpha)*(1.0f/K_);
  qv[k] = qk;
  cdf[k] = qk; __syncthreads();
  for (int off=1; off<K_; off<<=1){
    float add = (k>=off)? cdf[k-off] : 0.0f;
    __syncthreads();
    cdf[k] += add;
    __syncthreads();
  }
  float u = resample_u[b*K_ + k];
  int lo=0, cnt=K_;
  while (cnt>0){ int st=cnt>>1; if (cdf[lo+st] < u){ lo += st+1; cnt -= st+1; } else cnt = st; }
  int idx = min(lo, K_-1);

  float lr  = lw[idx] - logf(qv[idx]);
  float mx2; BLK_MAX(mx2, lr);
  float se2; BLK_SUM(se2, expf(lr-mx2));
  float lrn = lr - (mx2 + logf(se2));

  bool need = ess < 0.5f * K_;
  float flw = need ? lrn : lwn;
  lw_out[b*K_ + k] = flw;

  float mx3; BLK_MAX(mx3, flw);
  float se3; BLK_SUM(se3, expf(flw-mx3));
  float wk  = expf(flw - (mx3 + logf(se3)));
  wt[k] = wk;
  float sumw; BLK_SUM(sumw, wk);         // barriers inside make wt[] visible

#undef BLK_SUM
#undef BLK_MAX

  // weighted particle average: ws_h[h] = sum_k wt[k]*p[b,k,h]
  int h = k & (H_-1), half = k >> 7;
  float part = 0.f;
  const float* pb = &p[(size_t)b*K_*H_];
  for (int kk = half*128; kk < half*128 + 128; ++kk)
    part = fmaf(wt[kk], pb[(size_t)kk*H_ + h], part);
  red[k] = part; __syncthreads();
  if (k < H_) ws_h[k] = red[k] + red[k+H_];
  __syncthreads();

  if (k < O_) {
    float acc = sumw * b_out[k];
#pragma unroll 8
    for (int hh = 0; hh < H_; ++hh) acc = fmaf(ws_h[hh], W_out[hh*O_ + k], acc);
    out0[b*O_ + k] = acc;
  }

  // in-place gather if resampling triggers (chunked read->sync->write)
  if (need) {
    const float* src = &p[((size_t)b*K_ + idx)*H_];
    float* dstp      = &p[((size_t)b*K_ + k  )*H_];
    float tmp[16];
    for (int c = 0; c < H_; c += 16){
#pragma unroll
      for (int t=0;t<16;++t) tmp[t]=src[c+t];
      __syncthreads();
#pragma unroll
      for (int t=0;t<16;++t) dstp[c+t]=tmp[t];
      __syncthreads();
    }
  }
}

extern "C" void kernel_launch(void* const* d_in, const int* in_sizes, int n_in,
                              void* d_out, int out_size, void* d_ws, size_t ws_size,
                              hipStream_t stream) {
  const float* x           = (const float*)d_in[0];
  const float* particles   = (const float*)d_in[1];
  const float* log_weights = (const float*)d_in[2];
  const float* noise       = (const float*)d_in[3];
  const float* resample_u  = (const float*)d_in[4];
  const float* Wx          = (const float*)d_in[5];
  const float* Wh          = (const float*)d_in[6];
  const float* bvec        = (const float*)d_in[7];
  const float* log_sigma   = (const float*)d_in[8];
  const float* W_out       = (const float*)d_in[9];
  const float* b_out       = (const float*)d_in[10];
  const float* alpha_logit = (const float*)d_in[11];

  float* out0   = (float*)d_out;
  float* p_out  = out0 + B_*O_;
  float* lw_out = p_out + (size_t)B_*K_*H_;

  prop_kernel<<<(B_*K_)/BP, 256, 0, stream>>>(
      x, particles, noise, Wx, Wh, bvec, log_sigma, p_out);
  finish_kernel<<<B_, 256, 0, stream>>>(
      log_weights, resample_u, W_out, b_out, alpha_logit, p_out, out0, lw_out);
}

// Round 10
// 105.204 us; speedup vs baseline: 3.6756x; 1.0033x over previous
//
#include <hip/hip_runtime.h>
#include <math.h>

#define B_ 256
#define K_ 256
#define H_ 128
#define I_ 64
#define O_ 64
#define NU 6
#define BP 64    // particles per block (4 waves x 16)
#define MW 16    // particles per wave

typedef short bf16x8 __attribute__((ext_vector_type(8)));  // 8 bf16 in 4 VGPRs
typedef float f32x4  __attribute__((ext_vector_type(4)));

// RNE float->bf16 bits
__device__ __forceinline__ unsigned short f2bf(float f) {
  unsigned int u = __builtin_bit_cast(unsigned int, f);
  unsigned int r = (u + 0x7FFFu + ((u >> 16) & 1u)) >> 16;
  return (unsigned short)r;
}

// XOR-swizzled byte offset in a [rows][128] bf16 tile (row stride 256B, T2-style).
__device__ __forceinline__ unsigned int swz(unsigned int row, unsigned int col) {
  return (row * 256u + col * 2u) ^ ((row & 15u) << 4);
}

__device__ __forceinline__ float tanh_fast(float x) {
  float e = __expf(2.0f * x);
  return 1.0f - 2.0f * __builtin_amdgcn_rcpf(e + 1.0f);
}

// ---------------- propagation kernel (bf16 MFMA, dim-major D layout) ----------------
// D = Wh^T @ S^T per 16x16 tile: lane owns particle col (lr) and 4 contiguous dims.
// R7/R8 lesson: register buffers = NAMED arrays via macros (pointer-param lambdas
// forced scratch). R9 lesson: prefetch depth 2->3 was null -> not cover-limited.
// R10: occupancy lever. ONE f32 noise buffer (need ~110 VGPR) + launch_bounds(256,2)
// (empirical compiler cap 256/minwaves: R6 (256,3)->84, R7 (256,2)->128). VGPR<=128
// -> 4 waves/SIMD by regs; LDS 50KB -> 3 blocks/CU -> 12 waves/CU (was 8).
__global__ __launch_bounds__(256, 2) void prop_kernel(
    const float* __restrict__ x,          // [B,I]
    const float* __restrict__ particles,  // [B*K,H]
    const float* __restrict__ noise,      // [B*K,NU,H]
    const float* __restrict__ Wx,         // [I,H]
    const float* __restrict__ Wh,         // [H,H]
    const float* __restrict__ bvec,       // [H]
    const float* __restrict__ log_sigma,  // [H]
    float* __restrict__ p_out)            // [B*K,H]
{
  __shared__ __align__(16) unsigned short whT[H_ * H_]; // bf16 Wh^T [c][k], swizzled, 32KB
  __shared__ __align__(16) unsigned short sS[BP * H_];  // bf16 state [p][d], swizzled, 16KB
  __shared__ __align__(16) float xwx[H_];
  __shared__ __align__(16) float gsd[H_];

  const int tid  = threadIdx.x;
  const int lane = tid & 63;
  const int wave = tid >> 6;
  const int bk0  = blockIdx.x * BP;
  const int b    = bk0 >> 8;            // /K_
  const int lr   = lane & 15;           // particle col within wave tile
  const int lg   = lane >> 4;           // dim group 0..3

  const int myp = bk0 + wave * MW + lr; // this lane's particle row
  const float* prow = particles + (size_t)myp * H_ + lg * 4;
  const float* nrow = noise + (size_t)myp * NU * H_ + lg * 4;
  float* orow = p_out + (size_t)myp * H_ + lg * 4;

  // ---- issue early: initial state + first-unfold noise (overlaps staging) ----
  f32x4 s4[8], nA[8];
#pragma unroll
  for (int ct = 0; ct < 8; ++ct) s4[ct] = ((const f32x4*)prow)[ct * 4];
#pragma unroll
  for (int ct = 0; ct < 8; ++ct) nA[ct] = ((const f32x4*)nrow)[ct * 4];

  // ---- stage Wh^T as bf16 (swizzled) ----
#pragma unroll
  for (int it = 0; it < 16; ++it) {
    int idx = tid + it * 256;           // float4 index over Wh [k][c]
    int k   = idx >> 5;
    int c0  = (idx & 31) * 4;
    float4 v = ((const float4*)Wh)[idx];
    float vv[4] = {v.x, v.y, v.z, v.w};
#pragma unroll
    for (int e = 0; e < 4; ++e)
      *(unsigned short*)((char*)whT + swz(c0 + e, k)) = f2bf(vv[e]);
  }
  // ---- xwx = x@Wx + b, gsd = softplus(log_sigma)*sqrt(dt) ----
  if (tid < H_) {
    float acc = bvec[tid];
#pragma unroll 8
    for (int i = 0; i < I_; ++i) acc = fmaf(x[b * I_ + i], Wx[i * H_ + tid], acc);
    xwx[tid] = acc;
    gsd[tid] = log1pf(expf(log_sigma[tid])) * sqrtf(1.0f / 6.0f);
  }
  __syncthreads();

  const float dt = 1.0f / 6.0f;
  const int srow = wave * MW + lr;      // this lane's sS row

// macros keep all buffer accesses on NAMED arrays (static -> registers)
#define LOADN(buf, n_) do {                                                  \
    const f32x4* np = (const f32x4*)(nrow + (size_t)(n_) * H_);              \
    _Pragma("unroll")                                                        \
    for (int ct = 0; ct < 8; ++ct) buf[ct] = np[ct * 4];                     \
  } while (0)

#define STEP(nb) do {                                                        \
    _Pragma("unroll")                                                        \
    for (int ct = 0; ct < 8; ++ct) {                                         \
      unsigned lo_ = (unsigned)f2bf(s4[ct][0]) | ((unsigned)f2bf(s4[ct][1]) << 16); \
      unsigned hi_ = (unsigned)f2bf(s4[ct][2]) | ((unsigned)f2bf(s4[ct][3]) << 16); \
      uint2 pk_ = {lo_, hi_};                                                \
      *(uint2*)((char*)sS + swz(srow, ct * 16 + lg * 4)) = pk_;              \
    }                                                                        \
    bf16x8 bfrag0 = *(const bf16x8*)((char*)sS + swz(srow, 0 * 32 + lg * 8));\
    bf16x8 bfrag1 = *(const bf16x8*)((char*)sS + swz(srow, 1 * 32 + lg * 8));\
    bf16x8 bfrag2 = *(const bf16x8*)((char*)sS + swz(srow, 2 * 32 + lg * 8));\
    bf16x8 bfrag3 = *(const bf16x8*)((char*)sS + swz(srow, 3 * 32 + lg * 8));\
    _Pragma("unroll")                                                        \
    for (int ct = 0; ct < 8; ++ct) {                                         \
      f32x4 acc = *(const f32x4*)&xwx[ct * 16 + lg * 4];                     \
      bf16x8 af0 = *(const bf16x8*)((char*)whT + swz(ct * 16 + lr, 0 * 32 + lg * 8)); \
      acc = __builtin_amdgcn_mfma_f32_16x16x32_bf16(af0, bfrag0, acc, 0, 0, 0); \
      bf16x8 af1 = *(const bf16x8*)((char*)whT + swz(ct * 16 + lr, 1 * 32 + lg * 8)); \
      acc = __builtin_amdgcn_mfma_f32_16x16x32_bf16(af1, bfrag1, acc, 0, 0, 0); \
      bf16x8 af2 = *(const bf16x8*)((char*)whT + swz(ct * 16 + lr, 2 * 32 + lg * 8)); \
      acc = __builtin_amdgcn_mfma_f32_16x16x32_bf16(af2, bfrag2, acc, 0, 0, 0); \
      bf16x8 af3 = *(const bf16x8*)((char*)whT + swz(ct * 16 + lr, 3 * 32 + lg * 8)); \
      acc = __builtin_amdgcn_mfma_f32_16x16x32_bf16(af3, bfrag3, acc, 0, 0, 0); \
      f32x4 gs = *(const f32x4*)&gsd[ct * 16 + lg * 4];                      \
      _Pragma("unroll")                                                      \
      for (int r = 0; r < 4; ++r) {                                          \
        float t_  = tanh_fast(acc[r]);                                       \
        float sv_ = s4[ct][r];                                               \
        s4[ct][r] = fmaf(t_ - sv_, dt, sv_) + gs[r] * nb[ct][r];             \
      }                                                                      \
    }                                                                        \
  } while (0)

  // 6 unfolds, single noise buffer: reload issues right after prior EM consumed
  // it; cover = next STEP's GEMM phase (~800cy), residual hidden by 12 waves/CU.
  STEP(nA); LOADN(nA, 1);
  STEP(nA); LOADN(nA, 2);
  STEP(nA); LOADN(nA, 3);
  STEP(nA); LOADN(nA, 4);
  STEP(nA); LOADN(nA, 5);
  STEP(nA);

#undef LOADN
#undef STEP

  // write new particles (fp32, float4 coalesced)
#pragma unroll
  for (int ct = 0; ct < 8; ++ct) ((f32x4*)orow)[ct * 4] = s4[ct];
}

// ---------------- resampling + weighted output kernel ----------------
__device__ __forceinline__ float wave_sum(float v) {
#pragma unroll
  for (int off = 1; off < 64; off <<= 1) v += __shfl_xor(v, off, 64);
  return v;
}
__device__ __forceinline__ float wave_max(float v) {
#pragma unroll
  for (int off = 1; off < 64; off <<= 1) v = fmaxf(v, __shfl_xor(v, off, 64));
  return v;
}

// one block per batch, 256 threads = K particles
__global__ __launch_bounds__(256) void finish_kernel(
  const float* __restrict__ log_weights,   // [B,K]
  const float* __restrict__ resample_u,    // [B,K]
  const float* __restrict__ W_out,         // [H,O]
  const float* __restrict__ b_out,         // [O]
  const float* __restrict__ alpha_logit,   // [1]
  float* __restrict__ p,                   // [B*K,H] new particles (in d_out)
  float* __restrict__ out0,                // [B,O]
  float* __restrict__ lw_out)              // [B,K]
{
  const int b = blockIdx.x, k = threadIdx.x;
  const int wv = k >> 6;
  __shared__ float red[K_];
  __shared__ float lw[K_], qv[K_], cdf[K_], wt[K_];
  __shared__ float ws_h[H_];
  __shared__ float warr[4];

#define BLK_SUM(dst, v) do {                                   \
    float pw_ = wave_sum(v);                                   \
    __syncthreads();  /* protect warr reuse */                 \
    if ((k & 63) == 0) warr[wv] = pw_;                         \
    __syncthreads();                                           \
    dst = warr[0] + warr[1] + warr[2] + warr[3];               \
  } while (0)
#define BLK_MAX(dst, v) do {                                   \
    float pw_ = wave_max(v);                                   \
    __syncthreads();                                           \
    if ((k & 63) == 0) warr[wv] = pw_;                         \
    __syncthreads();                                           \
    dst = fmaxf(fmaxf(warr[0], warr[1]), fmaxf(warr[2], warr[3])); \
  } while (0)

  float lwk = log_weights[b*K_ + k];
  float mx;  BLK_MAX(mx, lwk);
  float se;  BLK_SUM(se, expf(lwk - mx));
  float lse = mx + logf(se);
  float lwn = lwk - lse;
  lw[k] = lwn;
  float w = expf(lwn);
  float sw2; BLK_SUM(sw2, w*w);          // barriers inside make lw[] visible
  float ess = 1.0f / sw2;

  float alpha = 1.0f/(1.0f + expf(-alpha_logit[0]));
  float qk = alpha*w + (1.0f-alpha)*(1.0f/K_);
  qv[k] = qk;
  cdf[k] = qk; __syncthreads();
  for (int off=1; off<K_; off<<=1){
    float add = (k>=off)? cdf[k-off] : 0.0f;
    __syncthreads();
    cdf[k] += add;
    __syncthreads();
  }
  float u = resample_u[b*K_ + k];
  int lo=0, cnt=K_;
  while (cnt>0){ int st=cnt>>1; if (cdf[lo+st] < u){ lo += st+1; cnt -= st+1; } else cnt = st; }
  int idx = min(lo, K_-1);

  float lr  = lw[idx] - logf(qv[idx]);
  float mx2; BLK_MAX(mx2, lr);
  float se2; BLK_SUM(se2, expf(lr-mx2));
  float lrn = lr - (mx2 + logf(se2));

  bool need = ess < 0.5f * K_;
  float flw = need ? lrn : lwn;
  lw_out[b*K_ + k] = flw;

  float mx3; BLK_MAX(mx3, flw);
  float se3; BLK_SUM(se3, expf(flw-mx3));
  float wk  = expf(flw - (mx3 + logf(se3)));
  wt[k] = wk;
  float sumw; BLK_SUM(sumw, wk);         // barriers inside make wt[] visible

#undef BLK_SUM
#undef BLK_MAX

  // weighted particle average: ws_h[h] = sum_k wt[k]*p[b,k,h]
  int h = k & (H_-1), half = k >> 7;
  float part = 0.f;
  const float* pb = &p[(size_t)b*K_*H_];
  for (int kk = half*128; kk < half*128 + 128; ++kk)
    part = fmaf(wt[kk], pb[(size_t)kk*H_ + h], part);
  red[k] = part; __syncthreads();
  if (k < H_) ws_h[k] = red[k] + red[k+H_];
  __syncthreads();

  if (k < O_) {
    float acc = sumw * b_out[k];
#pragma unroll 8
    for (int hh = 0; hh < H_; ++hh) acc = fmaf(ws_h[hh], W_out[hh*O_ + k], acc);
    out0[b*O_ + k] = acc;
  }

  // in-place gather if resampling triggers (chunked read->sync->write)
  if (need) {
    const float* src = &p[((size_t)b*K_ + idx)*H_];
    float* dstp      = &p[((size_t)b*K_ + k  )*H_];
    float tmp[16];
    for (int c = 0; c < H_; c += 16){
#pragma unroll
      for (int t=0;t<16;++t) tmp[t]=src[c+t];
      __syncthreads();
#pragma unroll
      for (int t=0;t<16;++t) dstp[c+t]=tmp[t];
      __syncthreads();
    }
  }
}

extern "C" void kernel_launch(void* const* d_in, const int* in_sizes, int n_in,
                              void* d_out, int out_size, void* d_ws, size_t ws_size,
                              hipStream_t stream) {
  const float* x           = (const float*)d_in[0];
  const float* particles   = (const float*)d_in[1];
  const float* log_weights = (const float*)d_in[2];
  const float* noise       = (const float*)d_in[3];
  const float* resample_u  = (const float*)d_in[4];
  const float* Wx          = (const float*)d_in[5];
  const float* Wh          = (const float*)d_in[6];
  const float* bvec        = (const float*)d_in[7];
  const float* log_sigma   = (const float*)d_in[8];
  const float* W_out       = (const float*)d_in[9];
  const float* b_out       = (const float*)d_in[10];
  const float* alpha_logit = (const float*)d_in[11];

  float* out0   = (float*)d_out;
  float* p_out  = out0 + B_*O_;
  float* lw_out = p_out + (size_t)B_*K_*H_;

  prop_kernel<<<(B_*K_)/BP, 256, 0, stream>>>(
      x, particles, noise, Wx, Wh, bvec, log_sigma, p_out);
  finish_kernel<<<B_, 256, 0, stream>>>(
      log_weights, resample_u, W_out, b_out, alpha_logit, p_out, out0, lw_out);
}